// Round 9
// baseline (690.557 us; speedup 1.0000x reference)
//
#include <hip/hip_runtime.h>

typedef unsigned long long u64;
typedef unsigned int u32;

#define FEAT 52
#define NPIX 2704          // 52*52
#define NANC 24336         // NPIX*9
#define PRE  12000
#define POST 2000
#define ROWW 192           // u64 words per mask row (12288 bits = 24 chunks * 512)
#define PADW 54            // padded x row width
#define PADS 2916          // 54*54 per channel

// ---- d_out layout (float elements) ----
#define ROIS_OFF 0
#define LOCS_OFF 8000
#define CLS_OFF  105344
#define OBJ_OFF  154016
#define CLS2_OFF 178352

// ---- ws layout (byte offsets) ----
#define OFF_W64   0ull          //  589824 f64 (3x3 weights, [g][ci][k][4] layout)
#define OFF_H64   4718592ull    //  692224 f64 (half 0 partial, includes bias)
#define OFF_REG64 10256384ull   //   97344 f64
#define OFF_SC64  11035136ull   //   24336 f64
#define OFF_ROI64 11229824ull   //   97344 f64
#define OFF_KEYS  12008576ull   //   32768 u64
#define OFF_SBOX  12270720ull   //   49152 f64
#define OFF_SAREA 12663936ull   //   12288 f64
#define OFF_SUPP  12762240ull   //     192 u64
#define OFF_MASK  12763776ull   //   12000*192 u64 = 18432000 B (end ~31.2 MB)
// xpad (2985984 B) and h64b (5537792 B) ALIAS the mask region: both are
// consumed by conv3/conv1 which finish before k_mask writes mask.
#define OFF_XPAD  OFF_MASK
#define OFF_H64B  (OFF_MASK + 2985984ull)

// ---------------------------------------------------------------- prep: pad x + w->f64 (merged)
__global__ __launch_bounds__(256) void k_prep(const float* __restrict__ x,
                                              float* __restrict__ xpad,
                                              const float* __restrict__ w,
                                              double* __restrict__ w64) {
    int b = blockIdx.x;
    if (b < 2916) {                            // pad x: 746496 elements
        int t = b * 256 + threadIdx.x;
        int ci = t / PADS, pos = t % PADS;
        int iy = pos / PADW, ix = pos % PADW;
        float v = 0.f;
        if (iy >= 1 && iy <= 52 && ix >= 1 && ix <= 52)
            v = x[ci * NPIX + (iy - 1) * FEAT + (ix - 1)];
        xpad[t] = v;
    } else {                                   // w -> f64 [g][ci][k][4]: 589824 elements
        int t = (b - 2916) * 256 + threadIdx.x;
        int j = t & 3;
        int r = t >> 2;
        int k = r % 9;
        int r2 = r / 9;
        int ci = r2 & 255;
        int g = r2 >> 8;
        w64[t] = (double)w[(((g * 4 + j) * 256) + ci) * 9 + k];
    }
}

// ---------------------------------------------------------------- conv 3x3 256->256 (f64)
__global__ __launch_bounds__(256) void k_conv3(const float* __restrict__ xpad,
                                               const double* __restrict__ w64,
                                               const float* __restrict__ b,
                                               double* __restrict__ h64,
                                               double* __restrict__ h64b) {
    const int p = blockIdx.x * 256 + threadIdx.x;
    const int o0 = blockIdx.y * 4;
    const int half = blockIdx.z;              // 0: ci 0..127 (+bias), 1: ci 128..255
    if (p >= NPIX) return;
    const int y = p / FEAT, xq = p % FEAT;
    double a0, a1, a2, a3;
    if (half == 0) {
        a0 = (double)b[o0+0]; a1 = (double)b[o0+1];
        a2 = (double)b[o0+2]; a3 = (double)b[o0+3];
    } else {
        a0 = a1 = a2 = a3 = 0.0;
    }
    const int c0 = half << 7;
    const float* xb = xpad + (size_t)c0 * PADS + y * PADW + xq;
    const double* wb = w64 + (size_t)blockIdx.y * 9216 + c0 * 36;
    #pragma unroll 2
    for (int ci = 0; ci < 128; ++ci) {
        float f0 = xb[0],   f1 = xb[1],   f2 = xb[2];
        float f3 = xb[54],  f4 = xb[55],  f5 = xb[56];
        float f6 = xb[108], f7 = xb[109], f8 = xb[110];
        double xv[9];
        xv[0]=(double)f0; xv[1]=(double)f1; xv[2]=(double)f2;
        xv[3]=(double)f3; xv[4]=(double)f4; xv[5]=(double)f5;
        xv[6]=(double)f6; xv[7]=(double)f7; xv[8]=(double)f8;
        const double* wr = wb + ci * 36;          // uniform -> s_load
        #pragma unroll
        for (int k = 0; k < 9; ++k) {
            a0 += xv[k] * wr[4*k+0];
            a1 += xv[k] * wr[4*k+1];
            a2 += xv[k] * wr[4*k+2];
            a3 += xv[k] * wr[4*k+3];
        }
        xb += PADS;
    }
    double* ho = (half == 0) ? h64 : h64b;
    ho[(o0+0)*NPIX + p] = a0;
    ho[(o0+1)*NPIX + p] = a1;
    ho[(o0+2)*NPIX + p] = a2;
    ho[(o0+3)*NPIX + p] = a3;
}

// ---------------------------------------------------------------- 1x1 convs (reg 36 + cls 18)
__global__ __launch_bounds__(64) void k_conv1(const double* __restrict__ h64,
                                              const double* __restrict__ h64b,
                                              const float* __restrict__ regw,
                                              const float* __restrict__ regb,
                                              const float* __restrict__ clsw,
                                              const float* __restrict__ clsb,
                                              float* __restrict__ out,
                                              double* __restrict__ reg64,
                                              double* __restrict__ score64) {
    const int g = blockIdx.y;                  // 0..5
    const int p = blockIdx.x * 64 + threadIdx.x;
    if (p >= NPIX) return;
    const bool isreg = (g < 4);
    const float* wbase = isreg ? (regw + g * 9 * 256) : (clsw + (g - 4) * 9 * 256);
    const float* bbase = isreg ? (regb + g * 9)       : (clsb + (g - 4) * 9);
    double acc[9];
    #pragma unroll
    for (int j = 0; j < 9; ++j) acc[j] = (double)bbase[j];
    #pragma unroll 4
    for (int ci = 0; ci < 256; ++ci) {
        double h = h64[ci * NPIX + p] + h64b[ci * NPIX + p];
        #pragma unroll
        for (int j = 0; j < 9; ++j)
            acc[j] += h * (double)wbase[j * 256 + ci];   // uniform -> s_load
    }
    #pragma unroll
    for (int j = 0; j < 9; ++j) {
        int oc = g * 9 + j;
        float v = (float)acc[j];
        if (isreg) {
            out[LOCS_OFF + p*36 + oc] = v;
            reg64[p*36 + oc] = acc[j];
        } else {
            int c = oc - 36;
            out[CLS_OFF  + p*18 + c] = v;
            out[CLS2_OFF + p*18 + c] = v;
            if (c & 1) {
                out[OBJ_OFF + p*9 + (c >> 1)] = v;
                score64[p*9 + (c >> 1)] = acc[j];
            }
        }
    }
}

// ---------------------------------------------------------------- decode + sort keys
__global__ __launch_bounds__(256) void k_decode(const double* __restrict__ reg64,
                                                const double* __restrict__ score64,
                                                double* __restrict__ roi64,
                                                u64* __restrict__ keys) {
    int t = blockIdx.x * 256 + threadIdx.x;    // grid 128 -> 32768
    if (t >= NANC) { keys[t] = ~0ull; return; }
    int pos = t / 9, a = t % 9;
    int py = pos / FEAT, px = pos % FEAT;
    int ri = a / 3, si = a % 3;
    double rat = (ri == 0) ? 0.5 : (ri == 1 ? 1.0 : 2.0);
    double scl = (si == 0) ? 4.0 : (si == 1 ? 8.0 : 16.0);
    double hA = 4.0 * scl * sqrt(rat);
    double wA = 4.0 * scl * sqrt(1.0 / rat);
    double cy0 = 4.0 * py + 2.0, cx0 = 4.0 * px + 2.0;
    // anchors go through f32 exactly like make_anchors().astype(float32)
    float y1f = (float)(cy0 - hA / 2.0), x1f = (float)(cx0 - wA / 2.0);
    float y2f = (float)(cy0 + hA / 2.0), x2f = (float)(cx0 + wA / 2.0);
    double ah = (double)y2f - (double)y1f, aw = (double)x2f - (double)x1f;
    double acy = (double)y1f + 0.5 * ah, acx = (double)x1f + 0.5 * aw;
    double l0 = reg64[4*t+0], l1 = reg64[4*t+1], l2 = reg64[4*t+2], l3 = reg64[4*t+3];
    double cy = l0 * ah + acy, cx = l1 * aw + acx;
    double hh = exp(l2) * ah,  ww = exp(l3) * aw;
    double r0 = fmin(fmax(cy - 0.5*hh, 0.0), 210.0);
    double r1 = fmin(fmax(cx - 0.5*ww, 0.0), 210.0);
    double r2 = fmin(fmax(cy + 0.5*hh, 0.0), 210.0);
    double r3 = fmin(fmax(cx + 0.5*ww, 0.0), 210.0);
    roi64[4*t+0] = r0; roi64[4*t+1] = r1; roi64[4*t+2] = r2; roi64[4*t+3] = r3;
    bool valid = (r2 - r0 >= 16.0) && (r3 - r1 >= 16.0);
    double m = valid ? score64[t] : -__builtin_huge_val();
    long long ll = __double_as_longlong(m);
    u64 u = (u64)ll;
    u64 mono = (ll < 0) ? ~u : (u ^ 0x8000000000000000ull); // ascending numeric
    keys[t] = ((~mono) & 0xFFFFFFFFFFFF0000ull) | (u64)t;   // asc key = desc score, stable
}

// ---------------------------------------------------------------- bitonic sort pieces
__global__ __launch_bounds__(1024) void k_sortA(u64* __restrict__ keys) {
    __shared__ u64 s[8192];                    // 64 KiB
    const int base = blockIdx.x * 8192;
    for (int t = threadIdx.x; t < 8192; t += 1024) s[t] = keys[base + t];
    __syncthreads();
    for (int k = 2; k <= 8192; k <<= 1) {
        for (int j = k >> 1; j > 0; j >>= 1) {
            for (int q = threadIdx.x; q < 4096; q += 1024) {
                int i = ((q & ~(j-1)) << 1) | (q & (j-1));
                int l = i | j;
                bool asc = (((base + i) & k) == 0);
                u64 A = s[i], B = s[l];
                bool sw = asc ? (A > B) : (A < B);
                if (sw) { s[i] = B; s[l] = A; }
            }
            __syncthreads();
        }
    }
    for (int t = threadIdx.x; t < 8192; t += 1024) keys[base + t] = s[t];
}

__global__ __launch_bounds__(1024) void k_sortB(u64* __restrict__ keys, int k) {
    __shared__ u64 s[8192];
    const int base = blockIdx.x * 8192;
    for (int t = threadIdx.x; t < 8192; t += 1024) s[t] = keys[base + t];
    __syncthreads();
    for (int j = 4096; j > 0; j >>= 1) {
        for (int q = threadIdx.x; q < 4096; q += 1024) {
            int i = ((q & ~(j-1)) << 1) | (q & (j-1));
            int l = i | j;
            bool asc = (((base + i) & k) == 0);
            u64 A = s[i], B = s[l];
            bool sw = asc ? (A > B) : (A < B);
            if (sw) { s[i] = B; s[l] = A; }
        }
        __syncthreads();
    }
    for (int t = threadIdx.x; t < 8192; t += 1024) keys[base + t] = s[t];
}

__global__ __launch_bounds__(256) void k_sortG(u64* __restrict__ keys, int k, int j) {
    int t = blockIdx.x * 256 + threadIdx.x;    // 16384 pairs
    int i = ((t & ~(j-1)) << 1) | (t & (j-1));
    int l = i | j;
    bool asc = ((i & k) == 0);
    u64 A = keys[i], B = keys[l];
    bool sw = asc ? (A > B) : (A < B);
    if (sw) { keys[i] = B; keys[l] = A; }
}

// ---------------------------------------------------------------- gather top-12000
__global__ __launch_bounds__(256) void k_gather(const u64* __restrict__ keys,
                                                const double* __restrict__ roi64,
                                                double* __restrict__ sbox,
                                                double* __restrict__ sarea,
                                                u64* __restrict__ suppinit) {
    int p = blockIdx.x * 256 + threadIdx.x;    // grid 48 -> 12288
    bool sup = true;
    if (p < PRE) {
        int idx = (int)(keys[p] & 0xFFFFull);
        double b0 = roi64[4*idx+0], b1 = roi64[4*idx+1];
        double b2 = roi64[4*idx+2], b3 = roi64[4*idx+3];
        sbox[4*p+0] = b0; sbox[4*p+1] = b1; sbox[4*p+2] = b2; sbox[4*p+3] = b3;
        sarea[p] = (b3 - b1 + 1.0) * (b2 - b0 + 1.0);
        sup = !((b2 - b0 >= 16.0) && (b3 - b1 >= 16.0));
    } else {
        sbox[4*p+0] = 0.0; sbox[4*p+1] = 0.0; sbox[4*p+2] = 0.0; sbox[4*p+3] = 0.0;
        sarea[p] = 1.0;
    }
    u64 ball = __ballot(sup);
    if ((threadIdx.x & 63) == 0) suppinit[p >> 6] = ball;
}

// ---------------------------------------------------------------- suppression bit matrix
__global__ __launch_bounds__(256) void k_mask(const double* __restrict__ sbox,
                                              const double* __restrict__ sarea,
                                              u64* __restrict__ mask) {
    const int jt = blockIdx.x, it = blockIdx.y;     // (12, 188)
    const int ib = it * 64, jb0 = jt * 1024;
    if (jb0 + 1023 <= ib) {                         // whole tile has j <= i -> zeros
        for (int t = threadIdx.x; t < 1024; t += 256) {
            int ti = t >> 4, w = t & 15;
            int i = ib + ti;
            if (i < PRE) mask[(size_t)i * ROWW + jt*16 + w] = 0ull;
        }
        return;
    }
    __shared__ double jbx[4096];
    __shared__ double jar[1024];
    for (int t = threadIdx.x; t < 4096; t += 256) jbx[t] = sbox[(size_t)jb0*4 + t];
    for (int t = threadIdx.x; t < 1024; t += 256) jar[t] = sarea[jb0 + t];
    __syncthreads();
    int ti = threadIdx.x >> 2;
    int i = ib + ti;
    if (i >= PRE) return;
    double iy1 = sbox[4*i+0], ix1 = sbox[4*i+1], iy2 = sbox[4*i+2], ix2 = sbox[4*i+3];
    double iar = sarea[i];
    for (int w = (threadIdx.x & 3); w < 16; w += 4) {
        u64 bits = 0ull;
        int q0 = w * 64;
        for (int l = 0; l < 64; ++l) {
            int q = q0 + l;
            double jy1 = jbx[4*q+0], jx1 = jbx[4*q+1], jy2 = jbx[4*q+2], jx2 = jbx[4*q+3];
            double yy1 = fmax(iy1, jy1), xx1 = fmax(ix1, jx1);
            double yy2 = fmin(iy2, jy2), xx2 = fmin(ix2, jx2);
            double iw = fmax(xx2 - xx1 + 1.0, 0.0);
            double ih = fmax(yy2 - yy1 + 1.0, 0.0);
            double inter = iw * ih;
            bool s = ((jb0 + q) > i) && (inter > 0.7 * (iar + jar[q] - inter));
            bits |= ((u64)s) << l;
        }
        mask[(size_t)i * ROWW + jt*16 + w] = bits;
    }
}

// ---------------------------------------------------------------- helpers for k_scan
__device__ inline u64 rdl64(u64 v, int l) {
    u32 lo = (u32)__builtin_amdgcn_readlane((int)(u32)v, l);
    u32 hi = (u32)__builtin_amdgcn_readlane((int)(u32)(v >> 32), l);
    return ((u64)hi << 32) | (u64)lo;
}

// SALU serial resolve of one 32-bit candidate half. z/km pinned to SGPRs;
// chain per kept = s_ff1 + v_readlane + s_andn2 (~15 cy) with only ONE
// readlane (self-word half) on the chain.
#define SCAN_HALF(ZVAR, KMVAR, RSRC, OFF)                                       \
    { u32 bp_, ln_, q_;                                                         \
      asm volatile(                                                             \
        "s_cmp_lg_u32 %[z], 0\n\t"                                              \
        "s_cbranch_scc0 Lend%=\n\t"                                             \
        "Lloop%=:\n\t"                                                          \
        "s_ff1_i32_b32 %[bp], %[z]\n\t"                                         \
        "s_add_i32 %[ln], %[bp], %[off]\n\t"                                    \
        "v_readlane_b32 %[q], %[r], %[ln]\n\t"                                  \
        "s_bitset1_b32 %[km], %[bp]\n\t"                                        \
        "s_bitset0_b32 %[z], %[bp]\n\t"                                         \
        "s_andn2_b32 %[z], %[z], %[q]\n\t"                                      \
        "s_cbranch_scc1 Lloop%=\n\t"                                            \
        "Lend%=:"                                                               \
        : [z]"+s"(ZVAR), [km]"+s"(KMVAR), [bp]"=&s"(bp_), [ln]"=&s"(ln_),       \
          [q]"=&s"(q_)                                                          \
        : [r]"v"(RSRC), [off]"i"(OFF)                                           \
        : "scc"); }

#define UPD(W) a##W |= rdl64(r##W, ln_);

#define RFL(expr) ((u32)__builtin_amdgcn_readfirstlane((int)(expr)))

#define GROUPX(G, UPDS)                                                         \
    if (!dn) {                                                                  \
        u32 zlo = RFL(~(s8[2*(G)]   | (u32)(a##G)));                            \
        u32 zhi = RFL(~(s8[2*(G)+1] | (u32)(a##G >> 32)));                      \
        u64 zl64 = ((u64)zhi << 32) | (u64)zlo;                                 \
        u64 r0=0,r1=0,r2=0,r3=0,r4=0,r5=0,r6=0,r7=0;                            \
        if ((zl64 >> lane) & 1ull) {                                            \
            const u64* rowp = &dbuf[cb][((G)*64 + lane)*9];                     \
            r0=rowp[0]; r1=rowp[1]; r2=rowp[2]; r3=rowp[3];                     \
            r4=rowp[4]; r5=rowp[5]; r6=rowp[6]; r7=rowp[7];                     \
        }                                                                       \
        u32 kmlo = 0, kmhi = 0;                                                 \
        if (zlo) SCAN_HALF(zlo, kmlo, (u32)(r##G), 0)                           \
        { u32 t0 = kmlo, sup_ = 0;                                              \
          while (t0) { int l2 = __builtin_ctz(t0); t0 &= t0 - 1;                \
              sup_ |= (u32)__builtin_amdgcn_readlane((int)(u32)(r##G >> 32), l2); } \
          zhi &= ~sup_; }                                                       \
        if (zhi) SCAN_HALF(zhi, kmhi, (u32)(r##G >> 32), 32)                    \
        u64 km64 = ((u64)kmhi << 32) | (u64)kmlo;                               \
        if (km64) {                                                             \
            int pc = __builtin_popcountll(km64);                                \
            int navail = POST - rk;                                             \
            int mylot = __builtin_amdgcn_mbcnt_hi((u32)(km64 >> 32),            \
                         __builtin_amdgcn_mbcnt_lo((u32)km64, 0));              \
            if (((km64 >> lane) & 1) && mylot < navail)                         \
                keptLDS[rk + mylot] = (u32)(c*512 + (G)*64 + lane);             \
            if (pc >= navail) { rk = POST; dn = true; }                         \
            else {                                                              \
                rk += pc;                                                       \
                u64 t_ = km64;                                                  \
                while (t_) { int ln_ = __builtin_ctzll(t_); t_ &= t_ - 1;       \
                             UPDS }                                             \
            }                                                                   \
        }                                                                       \
    }

// ---------------------------------------------------------------- NMS scan v5:
// 512 threads. Wave0: SALU asm serial resolve (32-bit halves), deferred
// cross-word updates. Waves 1-3: prefetch diag(c+1). Waves 4-7: shadow-JIT
// supp-partial(c+1) from kept known at chunk start. Phase B merges new kept.
__global__ __launch_bounds__(512) void k_scan(const u64* __restrict__ mask,
                                              const u64* __restrict__ suppinit,
                                              const double* __restrict__ sbox,
                                              float* __restrict__ rois) {
    __shared__ u64 dbuf[2][4608];     // [buf][row*9 + w], 512 rows x 8(+1 pad) words
    __shared__ u32 keptLDS[POST];     // global sorted indices of kept boxes
    __shared__ u32 supp8[2][16];      // chunk supp words as u32 pairs
    __shared__ int rankS, doneS;
    const int tid = threadIdx.x;
    const u32* suppinit32 = (const u32*)suppinit;

    if (tid < 16)                 supp8[0][tid]      = suppinit32[tid];       // chunk 0
    else if (tid < 32)            supp8[1][tid - 16] = suppinit32[tid];       // chunk 1
    if (tid == 0) { rankS = 0; doneS = 0; }
    for (int q = tid; q < 4096; q += 512) {
        int r = q >> 3, w = q & 7;
        dbuf[0][r*9 + w] = (r < PRE) ? mask[(size_t)r * ROWW + w] : 0ull;
    }
    __syncthreads();

    int rank0 = 0;                    // rank at start of current chunk (uniform)
    for (int c = 0; c < 24; ++c) {
        const int nc = c + 1;
        const int cb = c & 1, nb = nc & 1;
        if (tid < 64) {
            // ---------- wave 0: scan chunk c ----------
            const int lane = tid;
            const u32* s8 = supp8[cb];
            u64 a0=0,a1=0,a2=0,a3=0,a4=0,a5=0,a6=0,a7=0;
            int rk = __builtin_amdgcn_readfirstlane(rankS);
            bool dn = false;
            GROUPX(0, UPD(1)UPD(2)UPD(3)UPD(4)UPD(5)UPD(6)UPD(7))
            GROUPX(1, UPD(2)UPD(3)UPD(4)UPD(5)UPD(6)UPD(7))
            GROUPX(2, UPD(3)UPD(4)UPD(5)UPD(6)UPD(7))
            GROUPX(3, UPD(4)UPD(5)UPD(6)UPD(7))
            GROUPX(4, UPD(5)UPD(6)UPD(7))
            GROUPX(5, UPD(6)UPD(7))
            GROUPX(6, UPD(7))
            GROUPX(7, (void)ln_;)
            (void)a7;
            if (lane == 0) { rankS = rk; if (dn) doneS = 1; }
        } else if (tid < 256) {
            // ---------- waves 1..3: prefetch diag block of chunk nc ----------
            if (nc < 24) {
                for (int q = tid - 64; q < 4096; q += 192) {
                    int r = q >> 3, w = q & 7;
                    int i = nc*512 + r;
                    dbuf[nb][r*9 + w] = (i < PRE) ? mask[(size_t)i * ROWW + nc*8 + w] : 0ull;
                }
            }
        } else {
            // ---------- waves 4..7: supp-partial(nc) from kept[0, rank0) ----------
            if (nc < 24 && rank0 > 0) {
                u64 acc[8] = {0,0,0,0,0,0,0,0};
                for (int k = tid - 256; k < rank0; k += 256) {
                    const u64* rp = mask + (size_t)keptLDS[k] * ROWW + nc*8;
                    #pragma unroll
                    for (int w = 0; w < 8; ++w) acc[w] |= rp[w];
                }
                #pragma unroll
                for (int w = 0; w < 8; ++w) {
                    u64 v = acc[w];
                    #pragma unroll
                    for (int s = 1; s < 64; s <<= 1)
                        v |= (u64)__shfl_xor((unsigned long long)v, s, 64);
                    if ((tid & 63) == 0) {
                        if ((u32)v)         atomicOr(&supp8[nb][2*w],   (u32)v);
                        if ((u32)(v >> 32)) atomicOr(&supp8[nb][2*w+1], (u32)(v >> 32));
                    }
                }
            }
        }
        __syncthreads();                           // barrier 1
        if (doneS) break;
        if (nc >= 24) break;
        const int rk1 = rankS;
        // ---------- phase B: merge new kept [rank0, rk1) + init supp(c+2) ----------
        {
            int w = tid & 7;
            u64 acc = 0;
            for (int k = rank0 + (tid >> 3); k < rk1; k += 64)
                acc |= mask[(size_t)keptLDS[k] * ROWW + nc*8 + w];
            if ((u32)acc)         atomicOr(&supp8[nb][2*w],   (u32)acc);
            if ((u32)(acc >> 32)) atomicOr(&supp8[nb][2*w+1], (u32)(acc >> 32));
            if (tid < 16) supp8[cb][tid] = (c + 2 < 24) ? suppinit32[(c+2)*16 + tid] : 0u;
        }
        rank0 = rk1;
        __syncthreads();                           // barrier 2
    }
    __syncthreads();
    const int R = rankS;
    for (int r = tid; r < POST; r += 512) {
        if (r < R) {
            int p = (int)keptLDS[r];
            rois[4*r+0] = (float)sbox[4*p+0];
            rois[4*r+1] = (float)sbox[4*p+1];
            rois[4*r+2] = (float)sbox[4*p+2];
            rois[4*r+3] = (float)sbox[4*p+3];
        } // else stays zero (memset)
    }
}

// ---------------------------------------------------------------- launcher
extern "C" void kernel_launch(void* const* d_in, const int* in_sizes, int n_in,
                              void* d_out, int out_size, void* d_ws, size_t ws_size,
                              hipStream_t stream) {
    const float* x    = (const float*)d_in[0];
    const float* w1   = (const float*)d_in[1];
    const float* b1   = (const float*)d_in[2];
    const float* regw = (const float*)d_in[3];
    const float* regb = (const float*)d_in[4];
    const float* clsw = (const float*)d_in[5];
    const float* clsb = (const float*)d_in[6];
    float* out = (float*)d_out;

    char* ws = (char*)d_ws;
    double* w64    = (double*)(ws + OFF_W64);
    double* h64    = (double*)(ws + OFF_H64);
    double* reg64  = (double*)(ws + OFF_REG64);
    double* sc64   = (double*)(ws + OFF_SC64);
    double* roi64  = (double*)(ws + OFF_ROI64);
    u64*    keys   = (u64*)   (ws + OFF_KEYS);
    double* sbox   = (double*)(ws + OFF_SBOX);
    double* sarea  = (double*)(ws + OFF_SAREA);
    u64*    supp0  = (u64*)   (ws + OFF_SUPP);
    u64*    maskp  = (u64*)   (ws + OFF_MASK);
    float*  xpad   = (float*) (ws + OFF_XPAD);   // aliases mask region (used before k_mask)
    double* h64b   = (double*)(ws + OFF_H64B);   // aliases mask region (used before k_mask)

    (void)hipMemsetAsync(d_out, 0, 8000 * sizeof(float), stream);  // rois zero-padding

    k_prep<<<5220, 256, 0, stream>>>(x, xpad, w1, w64);
    k_conv3<<<dim3(11, 64, 2), 256, 0, stream>>>(xpad, w64, b1, h64, h64b);
    k_conv1<<<dim3(43, 6), 64, 0, stream>>>(h64, h64b, regw, regb, clsw, clsb, out, reg64, sc64);
    k_decode<<<128, 256, 0, stream>>>(reg64, sc64, roi64, keys);

    k_sortA<<<4, 1024, 0, stream>>>(keys);
    k_sortG<<<64, 256, 0, stream>>>(keys, 16384, 8192);
    k_sortB<<<4, 1024, 0, stream>>>(keys, 16384);
    k_sortG<<<64, 256, 0, stream>>>(keys, 32768, 16384);
    k_sortG<<<64, 256, 0, stream>>>(keys, 32768, 8192);
    k_sortB<<<4, 1024, 0, stream>>>(keys, 32768);

    k_gather<<<48, 256, 0, stream>>>(keys, roi64, sbox, sarea, supp0);
    k_mask<<<dim3(12, 188), 256, 0, stream>>>(sbox, sarea, maskp);
    k_scan<<<1, 512, 0, stream>>>(maskp, supp0, sbox, out + ROIS_OFF);
}

// Round 11
// 590.499 us; speedup vs baseline: 1.1694x; 1.1694x over previous
//
#include <hip/hip_runtime.h>

typedef unsigned long long u64;
typedef unsigned int u32;

#define FEAT 52
#define NPIX 2704          // 52*52
#define NANC 24336         // NPIX*9
#define PRE  12000
#define POST 2000
#define ROWW 192           // u64 words per mask row (12288 bits = 24 chunks * 512)
#define PADW 54            // padded x row width
#define PADS 2916          // 54*54 per channel

// ---- d_out layout (float elements) ----
#define ROIS_OFF 0
#define LOCS_OFF 8000
#define CLS_OFF  105344
#define OBJ_OFF  154016
#define CLS2_OFF 178352

// ---- ws layout (byte offsets) ----
#define OFF_W64   0ull          //  589824 f64 (3x3 weights, [g][ci][k][4] layout)
#define OFF_H64   4718592ull    //  692224 f64 (half 0 partial, includes bias)
#define OFF_REG64 10256384ull   //   97344 f64
#define OFF_SC64  11035136ull   //   24336 f64
#define OFF_ROI64 11229824ull   //   97344 f64
#define OFF_KEYS  12008576ull   //   32768 u64
#define OFF_SBOX  12270720ull   //   49152 f64
#define OFF_SAREA 12663936ull   //   12288 f64
#define OFF_SUPP  12762240ull   //     192 u64
#define OFF_MASK  12763776ull   //   12000*192 u64 = 18432000 B (end ~31.2 MB)
// xpad (2985984 B) and h64b (5537792 B) ALIAS the mask region: both are
// consumed by conv3/conv1 which finish before k_mask writes mask.
#define OFF_XPAD  OFF_MASK
#define OFF_H64B  (OFF_MASK + 2985984ull)

// ---------------------------------------------------------------- prep: pad x + w->f64 (merged)
__global__ __launch_bounds__(256) void k_prep(const float* __restrict__ x,
                                              float* __restrict__ xpad,
                                              const float* __restrict__ w,
                                              double* __restrict__ w64) {
    int b = blockIdx.x;
    if (b < 2916) {                            // pad x: 746496 elements
        int t = b * 256 + threadIdx.x;
        int ci = t / PADS, pos = t % PADS;
        int iy = pos / PADW, ix = pos % PADW;
        float v = 0.f;
        if (iy >= 1 && iy <= 52 && ix >= 1 && ix <= 52)
            v = x[ci * NPIX + (iy - 1) * FEAT + (ix - 1)];
        xpad[t] = v;
    } else {                                   // w -> f64 [g][ci][k][4]: 589824 elements
        int t = (b - 2916) * 256 + threadIdx.x;
        int j = t & 3;
        int r = t >> 2;
        int k = r % 9;
        int r2 = r / 9;
        int ci = r2 & 255;
        int g = r2 >> 8;
        w64[t] = (double)w[(((g * 4 + j) * 256) + ci) * 9 + k];
    }
}

// ---------------------------------------------------------------- conv 3x3 256->256 (f64)
__global__ __launch_bounds__(256) void k_conv3(const float* __restrict__ xpad,
                                               const double* __restrict__ w64,
                                               const float* __restrict__ b,
                                               double* __restrict__ h64,
                                               double* __restrict__ h64b) {
    const int p = blockIdx.x * 256 + threadIdx.x;
    const int o0 = blockIdx.y * 4;
    const int half = blockIdx.z;              // 0: ci 0..127 (+bias), 1: ci 128..255
    if (p >= NPIX) return;
    const int y = p / FEAT, xq = p % FEAT;
    double a0, a1, a2, a3;
    if (half == 0) {
        a0 = (double)b[o0+0]; a1 = (double)b[o0+1];
        a2 = (double)b[o0+2]; a3 = (double)b[o0+3];
    } else {
        a0 = a1 = a2 = a3 = 0.0;
    }
    const int c0 = half << 7;
    const float* xb = xpad + (size_t)c0 * PADS + y * PADW + xq;
    const double* wb = w64 + (size_t)blockIdx.y * 9216 + c0 * 36;
    #pragma unroll 2
    for (int ci = 0; ci < 128; ++ci) {
        float f0 = xb[0],   f1 = xb[1],   f2 = xb[2];
        float f3 = xb[54],  f4 = xb[55],  f5 = xb[56];
        float f6 = xb[108], f7 = xb[109], f8 = xb[110];
        double xv[9];
        xv[0]=(double)f0; xv[1]=(double)f1; xv[2]=(double)f2;
        xv[3]=(double)f3; xv[4]=(double)f4; xv[5]=(double)f5;
        xv[6]=(double)f6; xv[7]=(double)f7; xv[8]=(double)f8;
        const double* wr = wb + ci * 36;          // uniform -> s_load
        #pragma unroll
        for (int k = 0; k < 9; ++k) {
            a0 += xv[k] * wr[4*k+0];
            a1 += xv[k] * wr[4*k+1];
            a2 += xv[k] * wr[4*k+2];
            a3 += xv[k] * wr[4*k+3];
        }
        xb += PADS;
    }
    double* ho = (half == 0) ? h64 : h64b;
    ho[(o0+0)*NPIX + p] = a0;
    ho[(o0+1)*NPIX + p] = a1;
    ho[(o0+2)*NPIX + p] = a2;
    ho[(o0+3)*NPIX + p] = a3;
}

// ---------------------------------------------------------------- 1x1 convs (reg 36 + cls 18)
__global__ __launch_bounds__(64) void k_conv1(const double* __restrict__ h64,
                                              const double* __restrict__ h64b,
                                              const float* __restrict__ regw,
                                              const float* __restrict__ regb,
                                              const float* __restrict__ clsw,
                                              const float* __restrict__ clsb,
                                              float* __restrict__ out,
                                              double* __restrict__ reg64,
                                              double* __restrict__ score64) {
    const int g = blockIdx.y;                  // 0..5
    const int p = blockIdx.x * 64 + threadIdx.x;
    if (p >= NPIX) return;
    const bool isreg = (g < 4);
    const float* wbase = isreg ? (regw + g * 9 * 256) : (clsw + (g - 4) * 9 * 256);
    const float* bbase = isreg ? (regb + g * 9)       : (clsb + (g - 4) * 9);
    double acc[9];
    #pragma unroll
    for (int j = 0; j < 9; ++j) acc[j] = (double)bbase[j];
    #pragma unroll 4
    for (int ci = 0; ci < 256; ++ci) {
        double h = h64[ci * NPIX + p] + h64b[ci * NPIX + p];
        #pragma unroll
        for (int j = 0; j < 9; ++j)
            acc[j] += h * (double)wbase[j * 256 + ci];   // uniform -> s_load
    }
    #pragma unroll
    for (int j = 0; j < 9; ++j) {
        int oc = g * 9 + j;
        float v = (float)acc[j];
        if (isreg) {
            out[LOCS_OFF + p*36 + oc] = v;
            reg64[p*36 + oc] = acc[j];
        } else {
            int c = oc - 36;
            out[CLS_OFF  + p*18 + c] = v;
            out[CLS2_OFF + p*18 + c] = v;
            if (c & 1) {
                out[OBJ_OFF + p*9 + (c >> 1)] = v;
                score64[p*9 + (c >> 1)] = acc[j];
            }
        }
    }
}

// ---------------------------------------------------------------- decode + sort keys
__global__ __launch_bounds__(256) void k_decode(const double* __restrict__ reg64,
                                                const double* __restrict__ score64,
                                                double* __restrict__ roi64,
                                                u64* __restrict__ keys) {
    int t = blockIdx.x * 256 + threadIdx.x;    // grid 128 -> 32768
    if (t >= NANC) { keys[t] = ~0ull; return; }
    int pos = t / 9, a = t % 9;
    int py = pos / FEAT, px = pos % FEAT;
    int ri = a / 3, si = a % 3;
    double rat = (ri == 0) ? 0.5 : (ri == 1 ? 1.0 : 2.0);
    double scl = (si == 0) ? 4.0 : (si == 1 ? 8.0 : 16.0);
    double hA = 4.0 * scl * sqrt(rat);
    double wA = 4.0 * scl * sqrt(1.0 / rat);
    double cy0 = 4.0 * py + 2.0, cx0 = 4.0 * px + 2.0;
    // anchors go through f32 exactly like make_anchors().astype(float32)
    float y1f = (float)(cy0 - hA / 2.0), x1f = (float)(cx0 - wA / 2.0);
    float y2f = (float)(cy0 + hA / 2.0), x2f = (float)(cx0 + wA / 2.0);
    double ah = (double)y2f - (double)y1f, aw = (double)x2f - (double)x1f;
    double acy = (double)y1f + 0.5 * ah, acx = (double)x1f + 0.5 * aw;
    double l0 = reg64[4*t+0], l1 = reg64[4*t+1], l2 = reg64[4*t+2], l3 = reg64[4*t+3];
    double cy = l0 * ah + acy, cx = l1 * aw + acx;
    double hh = exp(l2) * ah,  ww = exp(l3) * aw;
    double r0 = fmin(fmax(cy - 0.5*hh, 0.0), 210.0);
    double r1 = fmin(fmax(cx - 0.5*ww, 0.0), 210.0);
    double r2 = fmin(fmax(cy + 0.5*hh, 0.0), 210.0);
    double r3 = fmin(fmax(cx + 0.5*ww, 0.0), 210.0);
    roi64[4*t+0] = r0; roi64[4*t+1] = r1; roi64[4*t+2] = r2; roi64[4*t+3] = r3;
    bool valid = (r2 - r0 >= 16.0) && (r3 - r1 >= 16.0);
    double m = valid ? score64[t] : -__builtin_huge_val();
    long long ll = __double_as_longlong(m);
    u64 u = (u64)ll;
    u64 mono = (ll < 0) ? ~u : (u ^ 0x8000000000000000ull); // ascending numeric
    keys[t] = ((~mono) & 0xFFFFFFFFFFFF0000ull) | (u64)t;   // asc key = desc score, stable
}

// ---------------------------------------------------------------- bitonic sort pieces
__global__ __launch_bounds__(1024) void k_sortA(u64* __restrict__ keys) {
    __shared__ u64 s[8192];                    // 64 KiB
    const int base = blockIdx.x * 8192;
    for (int t = threadIdx.x; t < 8192; t += 1024) s[t] = keys[base + t];
    __syncthreads();
    for (int k = 2; k <= 8192; k <<= 1) {
        for (int j = k >> 1; j > 0; j >>= 1) {
            for (int q = threadIdx.x; q < 4096; q += 1024) {
                int i = ((q & ~(j-1)) << 1) | (q & (j-1));
                int l = i | j;
                bool asc = (((base + i) & k) == 0);
                u64 A = s[i], B = s[l];
                bool sw = asc ? (A > B) : (A < B);
                if (sw) { s[i] = B; s[l] = A; }
            }
            __syncthreads();
        }
    }
    for (int t = threadIdx.x; t < 8192; t += 1024) keys[base + t] = s[t];
}

__global__ __launch_bounds__(1024) void k_sortB(u64* __restrict__ keys, int k) {
    __shared__ u64 s[8192];
    const int base = blockIdx.x * 8192;
    for (int t = threadIdx.x; t < 8192; t += 1024) s[t] = keys[base + t];
    __syncthreads();
    for (int j = 4096; j > 0; j >>= 1) {
        for (int q = threadIdx.x; q < 4096; q += 1024) {
            int i = ((q & ~(j-1)) << 1) | (q & (j-1));
            int l = i | j;
            bool asc = (((base + i) & k) == 0);
            u64 A = s[i], B = s[l];
            bool sw = asc ? (A > B) : (A < B);
            if (sw) { s[i] = B; s[l] = A; }
        }
        __syncthreads();
    }
    for (int t = threadIdx.x; t < 8192; t += 1024) keys[base + t] = s[t];
}

__global__ __launch_bounds__(256) void k_sortG(u64* __restrict__ keys, int k, int j) {
    int t = blockIdx.x * 256 + threadIdx.x;    // 16384 pairs
    int i = ((t & ~(j-1)) << 1) | (t & (j-1));
    int l = i | j;
    bool asc = ((i & k) == 0);
    u64 A = keys[i], B = keys[l];
    bool sw = asc ? (A > B) : (A < B);
    if (sw) { keys[i] = B; keys[l] = A; }
}

// ---------------------------------------------------------------- gather top-12000
__global__ __launch_bounds__(256) void k_gather(const u64* __restrict__ keys,
                                                const double* __restrict__ roi64,
                                                double* __restrict__ sbox,
                                                double* __restrict__ sarea,
                                                u64* __restrict__ suppinit) {
    int p = blockIdx.x * 256 + threadIdx.x;    // grid 48 -> 12288
    bool sup = true;
    if (p < PRE) {
        int idx = (int)(keys[p] & 0xFFFFull);
        double b0 = roi64[4*idx+0], b1 = roi64[4*idx+1];
        double b2 = roi64[4*idx+2], b3 = roi64[4*idx+3];
        sbox[4*p+0] = b0; sbox[4*p+1] = b1; sbox[4*p+2] = b2; sbox[4*p+3] = b3;
        sarea[p] = (b3 - b1 + 1.0) * (b2 - b0 + 1.0);
        sup = !((b2 - b0 >= 16.0) && (b3 - b1 >= 16.0));
    } else {
        sbox[4*p+0] = 0.0; sbox[4*p+1] = 0.0; sbox[4*p+2] = 0.0; sbox[4*p+3] = 0.0;
        sarea[p] = 1.0;
    }
    u64 ball = __ballot(sup);
    if ((threadIdx.x & 63) == 0) suppinit[p >> 6] = ball;
}

// ---------------------------------------------------------------- suppression bit matrix
// LDS padded layouts kill the 4-way same-bank conflict across w-groups:
// box q at jbx[4q + (q>>6)]  -> read addr 257*w + 4*l + k  (banks differ by 2 per w)
// area q at jar[q + (q>>6)]  -> read addr  65*w + l
__global__ __launch_bounds__(256) void k_mask(const double* __restrict__ sbox,
                                              const double* __restrict__ sarea,
                                              u64* __restrict__ mask) {
    const int jt = blockIdx.x, it = blockIdx.y;     // (12, 188)
    const int ib = it * 64, jb0 = jt * 1024;
    if (jb0 + 1023 <= ib) {                         // whole tile has j <= i -> zeros
        for (int t = threadIdx.x; t < 1024; t += 256) {
            int ti = t >> 4, w = t & 15;
            int i = ib + ti;
            if (i < PRE) mask[(size_t)i * ROWW + jt*16 + w] = 0ull;
        }
        return;
    }
    __shared__ double jbx[4112];   // 4096 + 16 pad
    __shared__ double jar[1040];   // 1024 + 16 pad
    for (int t = threadIdx.x; t < 4096; t += 256) jbx[t + (t >> 8)] = sbox[(size_t)jb0*4 + t];
    for (int t = threadIdx.x; t < 1024; t += 256) jar[t + (t >> 6)] = sarea[jb0 + t];
    __syncthreads();
    int ti = threadIdx.x >> 2;
    int i = ib + ti;
    if (i >= PRE) return;
    double iy1 = sbox[4*i+0], ix1 = sbox[4*i+1], iy2 = sbox[4*i+2], ix2 = sbox[4*i+3];
    double iar = sarea[i];
    for (int w = (threadIdx.x & 3); w < 16; w += 4) {
        const double* jb = &jbx[257 * w];
        const double* ja = &jar[65 * w];
        u64 bits = 0ull;
        int q0 = w * 64;
        for (int l = 0; l < 64; ++l) {
            double jy1 = jb[4*l+0], jx1 = jb[4*l+1], jy2 = jb[4*l+2], jx2 = jb[4*l+3];
            double yy1 = fmax(iy1, jy1), xx1 = fmax(ix1, jx1);
            double yy2 = fmin(iy2, jy2), xx2 = fmin(ix2, jx2);
            double iw = fmax(xx2 - xx1 + 1.0, 0.0);
            double ih = fmax(yy2 - yy1 + 1.0, 0.0);
            double inter = iw * ih;
            bool s = ((jb0 + q0 + l) > i) && (inter > 0.7 * (iar + ja[l] - inter));
            bits |= ((u64)s) << l;
        }
        mask[(size_t)i * ROWW + jt*16 + w] = bits;
    }
}

// ---------------------------------------------------------------- helpers for k_scan
__device__ inline u64 rdl64(u64 v, int l) {
    u32 lo = (u32)__builtin_amdgcn_readlane((int)(u32)v, l);
    u32 hi = (u32)__builtin_amdgcn_readlane((int)(u32)(v >> 32), l);
    return ((u64)hi << 32) | (u64)lo;
}
#define RFL64(lo, hi) ( ((u64)(u32)__builtin_amdgcn_readfirstlane((int)(hi)) << 32) \
                      | (u64)(u32)__builtin_amdgcn_readfirstlane((int)(lo)) )

// ---------------------------------------------------------------- NMS scan v4r:
// 512 threads. Wave0: v4 batch resolve (predicated row preload + rdl64
// broadcast per kept). Waves 1-3: prefetch diag(c+1). Waves 4-7: shadow-JIT
// supp-partial(c+1) from kept known at chunk start. Phase B merges new kept
// and inits supp(c+2) (race-free scaffolding from R9).
__global__ __launch_bounds__(512) void k_scan(const u64* __restrict__ mask,
                                              const u64* __restrict__ suppinit,
                                              const double* __restrict__ sbox,
                                              float* __restrict__ rois) {
    __shared__ u64 dbuf[2][4608];     // [buf][row*9 + w], 512 rows x 8(+1 pad) words
    __shared__ u32 keptLDS[POST];     // global sorted indices of kept boxes
    __shared__ u32 supp8[2][16];      // chunk supp words as u32 pairs
    __shared__ int rankS, doneS;
    const int tid = threadIdx.x;
    const u32* suppinit32 = (const u32*)suppinit;

    if (tid < 16)                 supp8[0][tid]      = suppinit32[tid];       // chunk 0
    else if (tid < 32)            supp8[1][tid - 16] = suppinit32[tid];       // chunk 1
    if (tid == 0) { rankS = 0; doneS = 0; }
    for (int q = tid; q < 4096; q += 512) {
        int r = q >> 3, w = q & 7;
        dbuf[0][r*9 + w] = (r < PRE) ? mask[(size_t)r * ROWW + w] : 0ull;
    }
    __syncthreads();

    int rank0 = 0;                    // rank at start of current chunk (uniform)
    for (int c = 0; c < 24; ++c) {
        const int nc = c + 1;
        const int cb = c & 1, nb = nc & 1;
        if (tid < 64) {
            // ---------- wave 0: scan chunk c (v4 compute) ----------
            const int lane = tid;
            u64 i0 = RFL64(supp8[cb][0],  supp8[cb][1]);
            u64 i1 = RFL64(supp8[cb][2],  supp8[cb][3]);
            u64 i2 = RFL64(supp8[cb][4],  supp8[cb][5]);
            u64 i3 = RFL64(supp8[cb][6],  supp8[cb][7]);
            u64 i4 = RFL64(supp8[cb][8],  supp8[cb][9]);
            u64 i5 = RFL64(supp8[cb][10], supp8[cb][11]);
            u64 i6 = RFL64(supp8[cb][12], supp8[cb][13]);
            u64 i7 = RFL64(supp8[cb][14], supp8[cb][15]);
            u64 a0=0,a1=0,a2=0,a3=0,a4=0,a5=0,a6=0,a7=0;
            int rk = __builtin_amdgcn_readfirstlane(rankS);
            bool dn = false;
#define GROUP(G)                                                                \
            if (!dn) {                                                          \
                u64 z = ~(i##G | a##G);                                         \
                if (z) {                                                        \
                    u64 r0=0,r1=0,r2=0,r3=0,r4=0,r5=0,r6=0,r7=0;                \
                    if ((z >> lane) & 1ull) {                                   \
                        const u64* rowp = &dbuf[cb][(G*64 + lane)*9];           \
                        r0=rowp[0]; r1=rowp[1]; r2=rowp[2]; r3=rowp[3];         \
                        r4=rowp[4]; r5=rowp[5]; r6=rowp[6]; r7=rowp[7];         \
                    }                                                           \
                    u64 keptm = 0;                                              \
                    while (z) {                                                 \
                        int bpos = (int)__builtin_ctzll(z);                     \
                        u64 q0=rdl64(r0,bpos), q1=rdl64(r1,bpos);               \
                        u64 q2=rdl64(r2,bpos), q3=rdl64(r3,bpos);               \
                        u64 q4=rdl64(r4,bpos), q5=rdl64(r5,bpos);               \
                        u64 q6=rdl64(r6,bpos), q7=rdl64(r7,bpos);               \
                        keptm |= (1ull << bpos);                                \
                        z &= ~(1ull << bpos) & ~q##G;                           \
                        a0|=q0; a1|=q1; a2|=q2; a3|=q3;                         \
                        a4|=q4; a5|=q5; a6|=q6; a7|=q7;                         \
                    }                                                           \
                    int pc = __builtin_popcountll(keptm);                       \
                    int navail = POST - rk;                                     \
                    int mylot = __builtin_amdgcn_mbcnt_hi((u32)(keptm >> 32),   \
                                 __builtin_amdgcn_mbcnt_lo((u32)keptm, 0));     \
                    if (((keptm >> lane) & 1) && mylot < navail)                \
                        keptLDS[rk + mylot] = (u32)(c*512 + G*64 + lane);       \
                    if (pc >= navail) { rk = POST; dn = true; }                 \
                    else rk += pc;                                              \
                }                                                               \
            }
            GROUP(0) GROUP(1) GROUP(2) GROUP(3)
            GROUP(4) GROUP(5) GROUP(6) GROUP(7)
#undef GROUP
            if (lane == 0) { rankS = rk; if (dn) doneS = 1; }
        } else if (tid < 256) {
            // ---------- waves 1..3: prefetch diag block of chunk nc ----------
            if (nc < 24) {
                for (int q = tid - 64; q < 4096; q += 192) {
                    int r = q >> 3, w = q & 7;
                    int i = nc*512 + r;
                    dbuf[nb][r*9 + w] = (i < PRE) ? mask[(size_t)i * ROWW + nc*8 + w] : 0ull;
                }
            }
        } else {
            // ---------- waves 4..7: supp-partial(nc) from kept[0, rank0) ----------
            if (nc < 24 && rank0 > 0) {
                u64 acc[8] = {0,0,0,0,0,0,0,0};
                for (int k = tid - 256; k < rank0; k += 256) {
                    const u64* rp = mask + (size_t)keptLDS[k] * ROWW + nc*8;
                    #pragma unroll
                    for (int w = 0; w < 8; ++w) acc[w] |= rp[w];
                }
                #pragma unroll
                for (int w = 0; w < 8; ++w) {
                    u64 v = acc[w];
                    #pragma unroll
                    for (int s = 1; s < 64; s <<= 1)
                        v |= (u64)__shfl_xor((unsigned long long)v, s, 64);
                    if ((tid & 63) == 0) {
                        if ((u32)v)         atomicOr(&supp8[nb][2*w],   (u32)v);
                        if ((u32)(v >> 32)) atomicOr(&supp8[nb][2*w+1], (u32)(v >> 32));
                    }
                }
            }
        }
        __syncthreads();                           // barrier 1
        if (doneS) break;
        if (nc >= 24) break;
        const int rk1 = rankS;
        // ---------- phase B: merge new kept [rank0, rk1) + init supp(c+2) ----------
        {
            int w = tid & 7;
            u64 acc = 0;
            for (int k = rank0 + (tid >> 3); k < rk1; k += 64)
                acc |= mask[(size_t)keptLDS[k] * ROWW + nc*8 + w];
            if ((u32)acc)         atomicOr(&supp8[nb][2*w],   (u32)acc);
            if ((u32)(acc >> 32)) atomicOr(&supp8[nb][2*w+1], (u32)(acc >> 32));
            if (tid < 16) supp8[cb][tid] = (c + 2 < 24) ? suppinit32[(c+2)*16 + tid] : 0u;
        }
        rank0 = rk1;
        __syncthreads();                           // barrier 2
    }
    __syncthreads();
    const int R = rankS;
    for (int r = tid; r < POST; r += 512) {
        if (r < R) {
            int p = (int)keptLDS[r];
            rois[4*r+0] = (float)sbox[4*p+0];
            rois[4*r+1] = (float)sbox[4*p+1];
            rois[4*r+2] = (float)sbox[4*p+2];
            rois[4*r+3] = (float)sbox[4*p+3];
        } // else stays zero (memset)
    }
}

// ---------------------------------------------------------------- launcher
extern "C" void kernel_launch(void* const* d_in, const int* in_sizes, int n_in,
                              void* d_out, int out_size, void* d_ws, size_t ws_size,
                              hipStream_t stream) {
    const float* x    = (const float*)d_in[0];
    const float* w1   = (const float*)d_in[1];
    const float* b1   = (const float*)d_in[2];
    const float* regw = (const float*)d_in[3];
    const float* regb = (const float*)d_in[4];
    const float* clsw = (const float*)d_in[5];
    const float* clsb = (const float*)d_in[6];
    float* out = (float*)d_out;

    char* ws = (char*)d_ws;
    double* w64    = (double*)(ws + OFF_W64);
    double* h64    = (double*)(ws + OFF_H64);
    double* reg64  = (double*)(ws + OFF_REG64);
    double* sc64   = (double*)(ws + OFF_SC64);
    double* roi64  = (double*)(ws + OFF_ROI64);
    u64*    keys   = (u64*)   (ws + OFF_KEYS);
    double* sbox   = (double*)(ws + OFF_SBOX);
    double* sarea  = (double*)(ws + OFF_SAREA);
    u64*    supp0  = (u64*)   (ws + OFF_SUPP);
    u64*    maskp  = (u64*)   (ws + OFF_MASK);
    float*  xpad   = (float*) (ws + OFF_XPAD);   // aliases mask region (used before k_mask)
    double* h64b   = (double*)(ws + OFF_H64B);   // aliases mask region (used before k_mask)

    (void)hipMemsetAsync(d_out, 0, 8000 * sizeof(float), stream);  // rois zero-padding

    k_prep<<<5220, 256, 0, stream>>>(x, xpad, w1, w64);
    k_conv3<<<dim3(11, 64, 2), 256, 0, stream>>>(xpad, w64, b1, h64, h64b);
    k_conv1<<<dim3(43, 6), 64, 0, stream>>>(h64, h64b, regw, regb, clsw, clsb, out, reg64, sc64);
    k_decode<<<128, 256, 0, stream>>>(reg64, sc64, roi64, keys);

    k_sortA<<<4, 1024, 0, stream>>>(keys);
    k_sortG<<<64, 256, 0, stream>>>(keys, 16384, 8192);
    k_sortB<<<4, 1024, 0, stream>>>(keys, 16384);
    k_sortG<<<64, 256, 0, stream>>>(keys, 32768, 16384);
    k_sortG<<<64, 256, 0, stream>>>(keys, 32768, 8192);
    k_sortB<<<4, 1024, 0, stream>>>(keys, 32768);

    k_gather<<<48, 256, 0, stream>>>(keys, roi64, sbox, sarea, supp0);
    k_mask<<<dim3(12, 188), 256, 0, stream>>>(sbox, sarea, maskp);
    k_scan<<<1, 512, 0, stream>>>(maskp, supp0, sbox, out + ROIS_OFF);
}

// Round 12
// 556.043 us; speedup vs baseline: 1.2419x; 1.0620x over previous
//
#include <hip/hip_runtime.h>

typedef unsigned long long u64;
typedef unsigned int u32;

#define FEAT 52
#define NPIX 2704          // 52*52
#define NANC 24336         // NPIX*9
#define PRE  12000
#define POST 2000
#define ROWW 192           // u64 words per mask row (12288 bits = 24 chunks * 512)
#define PADW 54            // padded x row width
#define PADS 2916          // 54*54 per channel

// ---- d_out layout (float elements) ----
#define ROIS_OFF 0
#define LOCS_OFF 8000
#define CLS_OFF  105344
#define OBJ_OFF  154016
#define CLS2_OFF 178352

// ---- ws layout (byte offsets) ----
#define OFF_W64   0ull          //  589824 f64 (3x3 weights, [g][ci][k][4] layout)
#define OFF_H64   4718592ull    //  692224 f64 (half 0 partial, includes bias)
#define OFF_REG64 10256384ull   //   97344 f64
#define OFF_SC64  11035136ull   //   24336 f64
#define OFF_ROI64 11229824ull   //   97344 f64
#define OFF_KEYS  12008576ull   //   32768 u64
#define OFF_SBOX  12270720ull   //   49152 f64
#define OFF_SAREA 12663936ull   //   12288 f64
#define OFF_SUPP  12762240ull   //     192 u64
#define OFF_MASK  12763776ull   //   12000*192 u64 = 18432000 B (end ~31.2 MB)
// xpad (2985984 B) and h64b (5537792 B) ALIAS the mask region: both are
// consumed by conv3/conv1 which finish before k_mask writes mask.
#define OFF_XPAD  OFF_MASK
#define OFF_H64B  (OFF_MASK + 2985984ull)

// ---------------------------------------------------------------- prep: pad x + w->f64 (merged)
__global__ __launch_bounds__(256) void k_prep(const float* __restrict__ x,
                                              float* __restrict__ xpad,
                                              const float* __restrict__ w,
                                              double* __restrict__ w64) {
    int b = blockIdx.x;
    if (b < 2916) {                            // pad x: 746496 elements
        int t = b * 256 + threadIdx.x;
        int ci = t / PADS, pos = t % PADS;
        int iy = pos / PADW, ix = pos % PADW;
        float v = 0.f;
        if (iy >= 1 && iy <= 52 && ix >= 1 && ix <= 52)
            v = x[ci * NPIX + (iy - 1) * FEAT + (ix - 1)];
        xpad[t] = v;
    } else {                                   // w -> f64 [g][ci][k][4]: 589824 elements
        int t = (b - 2916) * 256 + threadIdx.x;
        int j = t & 3;
        int r = t >> 2;
        int k = r % 9;
        int r2 = r / 9;
        int ci = r2 & 255;
        int g = r2 >> 8;
        w64[t] = (double)w[(((g * 4 + j) * 256) + ci) * 9 + k];
    }
}

// ---------------------------------------------------------------- conv 3x3 256->256 (f64)
__global__ __launch_bounds__(256) void k_conv3(const float* __restrict__ xpad,
                                               const double* __restrict__ w64,
                                               const float* __restrict__ b,
                                               double* __restrict__ h64,
                                               double* __restrict__ h64b) {
    const int p = blockIdx.x * 256 + threadIdx.x;
    const int o0 = blockIdx.y * 4;
    const int half = blockIdx.z;              // 0: ci 0..127 (+bias), 1: ci 128..255
    if (p >= NPIX) return;
    const int y = p / FEAT, xq = p % FEAT;
    double a0, a1, a2, a3;
    if (half == 0) {
        a0 = (double)b[o0+0]; a1 = (double)b[o0+1];
        a2 = (double)b[o0+2]; a3 = (double)b[o0+3];
    } else {
        a0 = a1 = a2 = a3 = 0.0;
    }
    const int c0 = half << 7;
    const float* xb = xpad + (size_t)c0 * PADS + y * PADW + xq;
    const double* wb = w64 + (size_t)blockIdx.y * 9216 + c0 * 36;
    #pragma unroll 2
    for (int ci = 0; ci < 128; ++ci) {
        float f0 = xb[0],   f1 = xb[1],   f2 = xb[2];
        float f3 = xb[54],  f4 = xb[55],  f5 = xb[56];
        float f6 = xb[108], f7 = xb[109], f8 = xb[110];
        double xv[9];
        xv[0]=(double)f0; xv[1]=(double)f1; xv[2]=(double)f2;
        xv[3]=(double)f3; xv[4]=(double)f4; xv[5]=(double)f5;
        xv[6]=(double)f6; xv[7]=(double)f7; xv[8]=(double)f8;
        const double* wr = wb + ci * 36;          // uniform -> s_load
        #pragma unroll
        for (int k = 0; k < 9; ++k) {
            a0 += xv[k] * wr[4*k+0];
            a1 += xv[k] * wr[4*k+1];
            a2 += xv[k] * wr[4*k+2];
            a3 += xv[k] * wr[4*k+3];
        }
        xb += PADS;
    }
    double* ho = (half == 0) ? h64 : h64b;
    ho[(o0+0)*NPIX + p] = a0;
    ho[(o0+1)*NPIX + p] = a1;
    ho[(o0+2)*NPIX + p] = a2;
    ho[(o0+3)*NPIX + p] = a3;
}

// ---------------------------------------------------------------- 1x1 convs (reg 36 + cls 18)
__global__ __launch_bounds__(64) void k_conv1(const double* __restrict__ h64,
                                              const double* __restrict__ h64b,
                                              const float* __restrict__ regw,
                                              const float* __restrict__ regb,
                                              const float* __restrict__ clsw,
                                              const float* __restrict__ clsb,
                                              float* __restrict__ out,
                                              double* __restrict__ reg64,
                                              double* __restrict__ score64) {
    const int g = blockIdx.y;                  // 0..5
    const int p = blockIdx.x * 64 + threadIdx.x;
    if (p >= NPIX) return;
    const bool isreg = (g < 4);
    const float* wbase = isreg ? (regw + g * 9 * 256) : (clsw + (g - 4) * 9 * 256);
    const float* bbase = isreg ? (regb + g * 9)       : (clsb + (g - 4) * 9);
    double acc[9];
    #pragma unroll
    for (int j = 0; j < 9; ++j) acc[j] = (double)bbase[j];
    #pragma unroll 4
    for (int ci = 0; ci < 256; ++ci) {
        double h = h64[ci * NPIX + p] + h64b[ci * NPIX + p];
        #pragma unroll
        for (int j = 0; j < 9; ++j)
            acc[j] += h * (double)wbase[j * 256 + ci];   // uniform -> s_load
    }
    #pragma unroll
    for (int j = 0; j < 9; ++j) {
        int oc = g * 9 + j;
        float v = (float)acc[j];
        if (isreg) {
            out[LOCS_OFF + p*36 + oc] = v;
            reg64[p*36 + oc] = acc[j];
        } else {
            int c = oc - 36;
            out[CLS_OFF  + p*18 + c] = v;
            out[CLS2_OFF + p*18 + c] = v;
            if (c & 1) {
                out[OBJ_OFF + p*9 + (c >> 1)] = v;
                score64[p*9 + (c >> 1)] = acc[j];
            }
        }
    }
}

// ---------------------------------------------------------------- decode + sort keys
__global__ __launch_bounds__(256) void k_decode(const double* __restrict__ reg64,
                                                const double* __restrict__ score64,
                                                double* __restrict__ roi64,
                                                u64* __restrict__ keys) {
    int t = blockIdx.x * 256 + threadIdx.x;    // grid 128 -> 32768
    if (t >= NANC) { keys[t] = ~0ull; return; }
    int pos = t / 9, a = t % 9;
    int py = pos / FEAT, px = pos % FEAT;
    int ri = a / 3, si = a % 3;
    double rat = (ri == 0) ? 0.5 : (ri == 1 ? 1.0 : 2.0);
    double scl = (si == 0) ? 4.0 : (si == 1 ? 8.0 : 16.0);
    double hA = 4.0 * scl * sqrt(rat);
    double wA = 4.0 * scl * sqrt(1.0 / rat);
    double cy0 = 4.0 * py + 2.0, cx0 = 4.0 * px + 2.0;
    // anchors go through f32 exactly like make_anchors().astype(float32)
    float y1f = (float)(cy0 - hA / 2.0), x1f = (float)(cx0 - wA / 2.0);
    float y2f = (float)(cy0 + hA / 2.0), x2f = (float)(cx0 + wA / 2.0);
    double ah = (double)y2f - (double)y1f, aw = (double)x2f - (double)x1f;
    double acy = (double)y1f + 0.5 * ah, acx = (double)x1f + 0.5 * aw;
    double l0 = reg64[4*t+0], l1 = reg64[4*t+1], l2 = reg64[4*t+2], l3 = reg64[4*t+3];
    double cy = l0 * ah + acy, cx = l1 * aw + acx;
    double hh = exp(l2) * ah,  ww = exp(l3) * aw;
    double r0 = fmin(fmax(cy - 0.5*hh, 0.0), 210.0);
    double r1 = fmin(fmax(cx - 0.5*ww, 0.0), 210.0);
    double r2 = fmin(fmax(cy + 0.5*hh, 0.0), 210.0);
    double r3 = fmin(fmax(cx + 0.5*ww, 0.0), 210.0);
    roi64[4*t+0] = r0; roi64[4*t+1] = r1; roi64[4*t+2] = r2; roi64[4*t+3] = r3;
    bool valid = (r2 - r0 >= 16.0) && (r3 - r1 >= 16.0);
    double m = valid ? score64[t] : -__builtin_huge_val();
    long long ll = __double_as_longlong(m);
    u64 u = (u64)ll;
    u64 mono = (ll < 0) ? ~u : (u ^ 0x8000000000000000ull); // ascending numeric
    keys[t] = ((~mono) & 0xFFFFFFFFFFFF0000ull) | (u64)t;   // asc key = desc score, stable
}

// ---------------------------------------------------------------- bitonic sort pieces
__global__ __launch_bounds__(1024) void k_sortA(u64* __restrict__ keys) {
    __shared__ u64 s[8192];                    // 64 KiB
    const int base = blockIdx.x * 8192;
    for (int t = threadIdx.x; t < 8192; t += 1024) s[t] = keys[base + t];
    __syncthreads();
    for (int k = 2; k <= 8192; k <<= 1) {
        for (int j = k >> 1; j > 0; j >>= 1) {
            for (int q = threadIdx.x; q < 4096; q += 1024) {
                int i = ((q & ~(j-1)) << 1) | (q & (j-1));
                int l = i | j;
                bool asc = (((base + i) & k) == 0);
                u64 A = s[i], B = s[l];
                bool sw = asc ? (A > B) : (A < B);
                if (sw) { s[i] = B; s[l] = A; }
            }
            __syncthreads();
        }
    }
    for (int t = threadIdx.x; t < 8192; t += 1024) keys[base + t] = s[t];
}

__global__ __launch_bounds__(1024) void k_sortB(u64* __restrict__ keys, int k) {
    __shared__ u64 s[8192];
    const int base = blockIdx.x * 8192;
    for (int t = threadIdx.x; t < 8192; t += 1024) s[t] = keys[base + t];
    __syncthreads();
    for (int j = 4096; j > 0; j >>= 1) {
        for (int q = threadIdx.x; q < 4096; q += 1024) {
            int i = ((q & ~(j-1)) << 1) | (q & (j-1));
            int l = i | j;
            bool asc = (((base + i) & k) == 0);
            u64 A = s[i], B = s[l];
            bool sw = asc ? (A > B) : (A < B);
            if (sw) { s[i] = B; s[l] = A; }
        }
        __syncthreads();
    }
    for (int t = threadIdx.x; t < 8192; t += 1024) keys[base + t] = s[t];
}

__global__ __launch_bounds__(256) void k_sortG(u64* __restrict__ keys, int k, int j) {
    int t = blockIdx.x * 256 + threadIdx.x;    // 16384 pairs
    int i = ((t & ~(j-1)) << 1) | (t & (j-1));
    int l = i | j;
    bool asc = ((i & k) == 0);
    u64 A = keys[i], B = keys[l];
    bool sw = asc ? (A > B) : (A < B);
    if (sw) { keys[i] = B; keys[l] = A; }
}

// ---------------------------------------------------------------- gather top-12000
__global__ __launch_bounds__(256) void k_gather(const u64* __restrict__ keys,
                                                const double* __restrict__ roi64,
                                                double* __restrict__ sbox,
                                                double* __restrict__ sarea,
                                                u64* __restrict__ suppinit) {
    int p = blockIdx.x * 256 + threadIdx.x;    // grid 48 -> 12288
    bool sup = true;
    if (p < PRE) {
        int idx = (int)(keys[p] & 0xFFFFull);
        double b0 = roi64[4*idx+0], b1 = roi64[4*idx+1];
        double b2 = roi64[4*idx+2], b3 = roi64[4*idx+3];
        sbox[4*p+0] = b0; sbox[4*p+1] = b1; sbox[4*p+2] = b2; sbox[4*p+3] = b3;
        sarea[p] = (b3 - b1 + 1.0) * (b2 - b0 + 1.0);
        sup = !((b2 - b0 >= 16.0) && (b3 - b1 >= 16.0));
    } else {
        sbox[4*p+0] = 0.0; sbox[4*p+1] = 0.0; sbox[4*p+2] = 0.0; sbox[4*p+3] = 0.0;
        sarea[p] = 1.0;
    }
    u64 ball = __ballot(sup);
    if ((threadIdx.x & 63) == 0) suppinit[p >> 6] = ball;
}

// ---------------------------------------------------------------- suppression bit matrix
// LDS padded layouts kill the 4-way same-bank conflict across w-groups.
__global__ __launch_bounds__(256) void k_mask(const double* __restrict__ sbox,
                                              const double* __restrict__ sarea,
                                              u64* __restrict__ mask) {
    const int jt = blockIdx.x, it = blockIdx.y;     // (12, 188)
    const int ib = it * 64, jb0 = jt * 1024;
    if (jb0 + 1023 <= ib) {                         // whole tile has j <= i -> zeros
        for (int t = threadIdx.x; t < 1024; t += 256) {
            int ti = t >> 4, w = t & 15;
            int i = ib + ti;
            if (i < PRE) mask[(size_t)i * ROWW + jt*16 + w] = 0ull;
        }
        return;
    }
    __shared__ double jbx[4112];   // 4096 + 16 pad
    __shared__ double jar[1040];   // 1024 + 16 pad
    for (int t = threadIdx.x; t < 4096; t += 256) jbx[t + (t >> 8)] = sbox[(size_t)jb0*4 + t];
    for (int t = threadIdx.x; t < 1024; t += 256) jar[t + (t >> 6)] = sarea[jb0 + t];
    __syncthreads();
    int ti = threadIdx.x >> 2;
    int i = ib + ti;
    if (i >= PRE) return;
    double iy1 = sbox[4*i+0], ix1 = sbox[4*i+1], iy2 = sbox[4*i+2], ix2 = sbox[4*i+3];
    double iar = sarea[i];
    for (int w = (threadIdx.x & 3); w < 16; w += 4) {
        const double* jb = &jbx[257 * w];
        const double* ja = &jar[65 * w];
        u64 bits = 0ull;
        int q0 = w * 64;
        for (int l = 0; l < 64; ++l) {
            double jy1 = jb[4*l+0], jx1 = jb[4*l+1], jy2 = jb[4*l+2], jx2 = jb[4*l+3];
            double yy1 = fmax(iy1, jy1), xx1 = fmax(ix1, jx1);
            double yy2 = fmin(iy2, jy2), xx2 = fmin(ix2, jx2);
            double iw = fmax(xx2 - xx1 + 1.0, 0.0);
            double ih = fmax(yy2 - yy1 + 1.0, 0.0);
            double inter = iw * ih;
            bool s = ((jb0 + q0 + l) > i) && (inter > 0.7 * (iar + ja[l] - inter));
            bits |= ((u64)s) << l;
        }
        mask[(size_t)i * ROWW + jt*16 + w] = bits;
    }
}

// ---------------------------------------------------------------- helpers for k_scan
__device__ inline u64 shflx64(u64 v, int m) {
    int lo = __shfl_xor((int)(u32)v, m, 64);
    int hi = __shfl_xor((int)(u32)(v >> 32), m, 64);
    return ((u64)(u32)hi << 32) | (u64)(u32)lo;
}
// 64x64 bit-matrix transpose across one wave: lane holds row x; returns
// lane's row of the transposed matrix. 6-stage butterfly (verified on 4x4).
__device__ inline u64 bitT64(u64 x, int lane) {
#define TS(d, Mlo) { u64 y = shflx64(x, d); \
    x = (lane & d) ? ((x & ~(Mlo)) | ((y >> d) & (Mlo))) \
                   : ((x & (Mlo))  | ((y & (Mlo)) << d)); }
    TS(32, 0x00000000FFFFFFFFull)
    TS(16, 0x0000FFFF0000FFFFull)
    TS(8,  0x00FF00FF00FF00FFull)
    TS(4,  0x0F0F0F0F0F0F0F0Full)
    TS(2,  0x3333333333333333ull)
    TS(1,  0x5555555555555555ull)
#undef TS
    return x;
}

// ---------------------------------------------------------------- NMS scan v6 (transposed):
// Diag 512x512 blocks stored as 64 bit-TRANSPOSED 64x64 subtiles in LDS:
// dbufT[(g*8+h)*64 + j] = column j of rows g*64.. restricted to word h.
// Wave0 in-group chain per kept: ctz -> (tg[g]>>i)&1 -> ballot (~25 cy), and
// cross-group suppression is (tg[h] & keptm)!=0 per GROUP, not per kept.
// Waves 1-7: prefetch+transpose diag(c+1) then shadow-JIT supp-partial(c+1).
__global__ __launch_bounds__(512) void k_scan(const u64* __restrict__ mask,
                                              const u64* __restrict__ suppinit,
                                              const double* __restrict__ sbox,
                                              float* __restrict__ rois) {
    __shared__ u64 dbufT[2][4096];    // [buf][(g*8+h)*64 + lane], 64 KiB
    __shared__ u32 keptLDS[POST];     // global sorted indices of kept boxes
    __shared__ u32 supp8[2][16];      // chunk supp words as u32 pairs
    __shared__ int rankS, doneS;
    const int tid = threadIdx.x;
    const u32* suppinit32 = (const u32*)suppinit;

    if (tid < 16)      supp8[0][tid]      = suppinit32[tid];       // chunk 0
    else if (tid < 32) supp8[1][tid - 16] = suppinit32[tid];       // chunk 1
    if (tid == 0) { rankS = 0; doneS = 0; }
    {   // prologue: all 8 waves transpose chunk 0 (wave w -> group g=w)
        const int w = tid >> 6, lane = tid & 63;
        const int g = w;
        int row = g*64 + lane;
        u64 rw[8];
        if (row < PRE) {
            const u64* rp = mask + (size_t)row * ROWW;
            #pragma unroll
            for (int h = 0; h < 8; ++h) rw[h] = rp[h];
        } else {
            #pragma unroll
            for (int h = 0; h < 8; ++h) rw[h] = 0ull;
        }
        #pragma unroll
        for (int h = 0; h < 8; ++h)
            dbufT[0][(g*8 + h)*64 + lane] = bitT64(rw[h], lane);
    }
    __syncthreads();

    int rank0 = 0;                    // rank at start of current chunk (uniform)
    for (int c = 0; c < 24; ++c) {
        const int nc = c + 1;
        const int cb = c & 1, nb = nc & 1;
        if (tid < 64) {
            // ---------- wave 0: scan chunk c on transposed subtiles ----------
            const int lane = tid;
            u32 sup = 0;              // bit h = candidate h*64+lane suppressed
            #pragma unroll
            for (int h = 0; h < 8; ++h)
                sup |= ((supp8[cb][2*h + (lane >> 5)] >> (lane & 31)) & 1u) << h;
            int rk = rankS;
            bool dn = false;
            for (int g = 0; g < 8; ++g) {
                bool agj = !((sup >> g) & 1u);
                u64 z = __ballot(agj);
                if (!z) continue;
                u64 tg[8];
                #pragma unroll
                for (int h = 0; h < 8; ++h) tg[h] = dbufT[cb][(g*8 + h)*64 + lane];
                u64 keptm = 0;
                while (z) {
                    int i = (int)__builtin_ctzll(z);
                    keptm |= (1ull << i);
                    agj = agj && !((tg[g] >> i) & 1ull);
                    u64 m2 = (i < 63) ? (~0ull << (i + 1)) : 0ull;
                    z = __ballot(agj) & m2;
                }
                int pc = __builtin_popcountll(keptm);
                int navail = POST - rk;
                int mylot = __builtin_amdgcn_mbcnt_hi((u32)(keptm >> 32),
                             __builtin_amdgcn_mbcnt_lo((u32)keptm, 0));
                if (((keptm >> lane) & 1) && mylot < navail)
                    keptLDS[rk + mylot] = (u32)(c*512 + g*64 + lane);
                if (pc >= navail) { rk = POST; dn = true; break; }
                rk += pc;
                #pragma unroll
                for (int h = 0; h < 8; ++h)
                    if (h > g && (tg[h] & keptm)) sup |= (1u << h);
            }
            if (lane == 0) { rankS = rk; if (dn) doneS = 1; }
        } else if (nc < 24) {
            const int w = tid >> 6, lane = tid & 63;   // w = 1..7
            // ---------- prefetch + bit-transpose diag block of chunk nc ----------
            for (int g = w - 1; g < 8; g += 7) {       // wave1: g0,g7; wave2..7: g1..g6
                int row = nc*512 + g*64 + lane;
                u64 rw[8];
                if (row < PRE) {
                    const u64* rp = mask + (size_t)row * ROWW + nc*8;
                    #pragma unroll
                    for (int h = 0; h < 8; ++h) rw[h] = rp[h];
                } else {
                    #pragma unroll
                    for (int h = 0; h < 8; ++h) rw[h] = 0ull;
                }
                #pragma unroll
                for (int h = 0; h < 8; ++h)
                    dbufT[nb][(g*8 + h)*64 + lane] = bitT64(rw[h], lane);
            }
            // ---------- shadow-JIT supp-partial(nc) from kept[0, rank0) ----------
            if (rank0 > 0) {
                u64 acc[8] = {0,0,0,0,0,0,0,0};
                for (int k = tid - 64; k < rank0; k += 448) {
                    const u64* rp = mask + (size_t)keptLDS[k] * ROWW + nc*8;
                    #pragma unroll
                    for (int h2 = 0; h2 < 8; ++h2) acc[h2] |= rp[h2];
                }
                #pragma unroll
                for (int h2 = 0; h2 < 8; ++h2) {
                    u64 v = acc[h2];
                    #pragma unroll
                    for (int s = 1; s < 64; s <<= 1)
                        v |= (u64)__shfl_xor((unsigned long long)v, s, 64);
                    if (lane == 0) {
                        if ((u32)v)         atomicOr(&supp8[nb][2*h2],   (u32)v);
                        if ((u32)(v >> 32)) atomicOr(&supp8[nb][2*h2+1], (u32)(v >> 32));
                    }
                }
            }
        }
        __syncthreads();                           // barrier 1
        if (doneS) break;
        if (nc >= 24) break;
        const int rk1 = rankS;
        // ---------- phase B: merge new kept [rank0, rk1) + init supp(c+2) ----------
        {
            int w = tid & 7;
            u64 acc = 0;
            for (int k = rank0 + (tid >> 3); k < rk1; k += 64)
                acc |= mask[(size_t)keptLDS[k] * ROWW + nc*8 + w];
            if ((u32)acc)         atomicOr(&supp8[nb][2*w],   (u32)acc);
            if ((u32)(acc >> 32)) atomicOr(&supp8[nb][2*w+1], (u32)(acc >> 32));
            if (tid < 16) supp8[cb][tid] = (c + 2 < 24) ? suppinit32[(c+2)*16 + tid] : 0u;
        }
        rank0 = rk1;
        __syncthreads();                           // barrier 2
    }
    __syncthreads();
    const int R = rankS;
    for (int r = tid; r < POST; r += 512) {
        if (r < R) {
            int p = (int)keptLDS[r];
            rois[4*r+0] = (float)sbox[4*p+0];
            rois[4*r+1] = (float)sbox[4*p+1];
            rois[4*r+2] = (float)sbox[4*p+2];
            rois[4*r+3] = (float)sbox[4*p+3];
        } // else stays zero (memset)
    }
}

// ---------------------------------------------------------------- launcher
extern "C" void kernel_launch(void* const* d_in, const int* in_sizes, int n_in,
                              void* d_out, int out_size, void* d_ws, size_t ws_size,
                              hipStream_t stream) {
    const float* x    = (const float*)d_in[0];
    const float* w1   = (const float*)d_in[1];
    const float* b1   = (const float*)d_in[2];
    const float* regw = (const float*)d_in[3];
    const float* regb = (const float*)d_in[4];
    const float* clsw = (const float*)d_in[5];
    const float* clsb = (const float*)d_in[6];
    float* out = (float*)d_out;

    char* ws = (char*)d_ws;
    double* w64    = (double*)(ws + OFF_W64);
    double* h64    = (double*)(ws + OFF_H64);
    double* reg64  = (double*)(ws + OFF_REG64);
    double* sc64   = (double*)(ws + OFF_SC64);
    double* roi64  = (double*)(ws + OFF_ROI64);
    u64*    keys   = (u64*)   (ws + OFF_KEYS);
    double* sbox   = (double*)(ws + OFF_SBOX);
    double* sarea  = (double*)(ws + OFF_SAREA);
    u64*    supp0  = (u64*)   (ws + OFF_SUPP);
    u64*    maskp  = (u64*)   (ws + OFF_MASK);
    float*  xpad   = (float*) (ws + OFF_XPAD);   // aliases mask region (used before k_mask)
    double* h64b   = (double*)(ws + OFF_H64B);   // aliases mask region (used before k_mask)

    (void)hipMemsetAsync(d_out, 0, 8000 * sizeof(float), stream);  // rois zero-padding

    k_prep<<<5220, 256, 0, stream>>>(x, xpad, w1, w64);
    k_conv3<<<dim3(11, 64, 2), 256, 0, stream>>>(xpad, w64, b1, h64, h64b);
    k_conv1<<<dim3(43, 6), 64, 0, stream>>>(h64, h64b, regw, regb, clsw, clsb, out, reg64, sc64);
    k_decode<<<128, 256, 0, stream>>>(reg64, sc64, roi64, keys);

    k_sortA<<<4, 1024, 0, stream>>>(keys);
    k_sortG<<<64, 256, 0, stream>>>(keys, 16384, 8192);
    k_sortB<<<4, 1024, 0, stream>>>(keys, 16384);
    k_sortG<<<64, 256, 0, stream>>>(keys, 32768, 16384);
    k_sortG<<<64, 256, 0, stream>>>(keys, 32768, 8192);
    k_sortB<<<4, 1024, 0, stream>>>(keys, 32768);

    k_gather<<<48, 256, 0, stream>>>(keys, roi64, sbox, sarea, supp0);
    k_mask<<<dim3(12, 188), 256, 0, stream>>>(sbox, sarea, maskp);
    k_scan<<<1, 512, 0, stream>>>(maskp, supp0, sbox, out + ROIS_OFF);
}